// Round 13
// baseline (29193.698 us; speedup 1.0000x reference)
//
#include <hip/hip_runtime.h>

// FFJORD density on MI355X (gfx950). B=65536 rows, DIM=128, HID=512, 32 RK4 steps x 4 evals.
// Round 15: R10/R11's fused structure (correct twice) with the remat trigger removed.
// R14 A/B: setprio NULL (barrier-locked waves, no role diversity). R10/R11's perf failure
// was scattered 2-byte acc-layout constant loads -> allocator remat'd them per eval
// (32GB scalar re-reads). Fix: vg_k writes g3/u DIRECTLY in per-thread-contiguous
// acc-packed layout (32 shorts/thread, loaded as 4x dwordx4 = proven no-remat pattern).
// Structure (4 barriers/eval): Z: h1=tanh(zs@W1z+..)->H1s + fac=(1-h1^2)*u regs | (2) |
// A-mfma: h1@W2 | (3a) | A-epi: h2->Hss, g2=g3*(1-h2^2)->H1s | (3b) |
// B: h2@W3+state->Zss ; D: g2@W2T, div=acc.fac in-reg -> div_s | (4) | div reduce.
// Deletes phases C+E (streaming VALU passes), 3 barriers, E's panel re-reads, u stream.
// 64-row blocks, 1024 thr, 16 waves, 1 block/CU (LDS 155KB), C=32768.
// Canaries: WRITE >> 178KB = spill; FETCH > 15GB/dispatch = remat.

#define DIMV 128
#define HIDV 512
#define ROWS 64
#define PAN_STR 536   // panel stride (shorts): 1072B, 16B-aligned
#define ZS_STR  136   // 272B, 16B-aligned

typedef float  floatx4 __attribute__((ext_vector_type(4)));
typedef short  short8  __attribute__((ext_vector_type(8)));
typedef unsigned int uintx4 __attribute__((ext_vector_type(4)));

static __device__ __forceinline__ unsigned short f2bf(float x) {
    union { float f; unsigned int u; } c; c.f = x;
    unsigned int u = c.u;
    u += 0x7FFFu + ((u >> 16) & 1u);   // round-to-nearest-even
    return (unsigned short)(u >> 16);
}
static __device__ __forceinline__ float bf2f(unsigned short h) {
    union { unsigned int u; float f; } c; c.u = ((unsigned int)h) << 16;
    return c.f;
}
static __device__ __forceinline__ float fast_tanh(float x) {
    x = fminf(8.0f, fmaxf(-8.0f, x));
    float e = exp2f(x * 2.8853900817779268f);            // exp(2x)
    return (e - 1.0f) * __builtin_amdgcn_rcpf(e + 1.0f); // (e-1)/(e+1)
}

// ---- weight packing: dst[(k>>3)*N*8 + n*8 + (k&7)] = bf16(W[k][n]) ------------
__global__ void pack_kernel(const float* __restrict__ src, unsigned short* __restrict__ dst,
                            int K, int N, int ld, int transpose) {
    int i = blockIdx.x * 256 + threadIdx.x;
    if (i >= K * N) return;
    int j  = i & 7;
    int n  = (i >> 3) % N;
    int k8 = (i >> 3) / N;
    int k  = k8 * 8 + j;
    float v = transpose ? src[n * ld + k] : src[k * ld + n];
    dst[i] = f2bf(v);
}

// ---- v-GEMM producer (g3 = v@W3^T, u = v@W1z): 128 rows x 256 cols per WG -----
// packacc: write acc-layout per-thread-contiguous blocks for ode_k's pinned constants:
//   dst[((row>>6)*1024 + tid_o)*32 + j], tid_o = wave_o*64 + quad_o*16 + l16_o,
//   j = m_o*8 + f_o*4 + pr*2 + h  (rows 64/block, m_o=rin>>4, quad_o=(rin>>2)&3,
//   pr=(rin>>1)&1, h=rin&1; cols: wave_o=col>>5, f_o=(col>>4)&1, l16_o=col&15).
__global__ __launch_bounds__(256, 2) void vg_k(const float* __restrict__ v,
                                               const unsigned short* __restrict__ Wp,
                                               unsigned short* __restrict__ out0,
                                               int packacc) {
    __shared__ __align__(16) unsigned short As[128 * 72];
    const int tid  = threadIdx.x;
    const int wave = tid >> 6, lane = tid & 63;
    const int quad = lane >> 4, l16 = lane & 15;
    const int row0 = blockIdx.x * 128;
    const int colw = blockIdx.y * 256 + wave * 64;

    floatx4 acc[8][4];
    #pragma unroll
    for (int m = 0; m < 8; ++m)
        #pragma unroll
        for (int f = 0; f < 4; ++f) { floatx4 zz = {0.f,0.f,0.f,0.f}; acc[m][f] = zz; }

    for (int k0 = 0; k0 < 128; k0 += 64) {
        __syncthreads();
        {
            const int r  = tid >> 3;
            const int cc = (tid & 7) << 3;
            #pragma unroll
            for (int i = 0; i < 4; ++i) {
                const int rr = r + (i << 5);
                const size_t base = (size_t)(row0 + rr) * 128 + k0 + cc;
                float vals[8];
                *(float4*)&vals[0] = *(const float4*)&v[base];
                *(float4*)&vals[4] = *(const float4*)&v[base + 4];
                short8 sv;
                #pragma unroll
                for (int j = 0; j < 8; ++j) sv[j] = (short)f2bf(vals[j]);
                *reinterpret_cast<short8*>(&As[rr * 72 + cc]) = sv;
            }
        }
        __syncthreads();
        #pragma unroll
        for (int kt = 0; kt < 2; ++kt) {
            const int k8 = (k0 >> 3) + (kt << 2) + quad;
            short8 b[4];
            #pragma unroll
            for (int f = 0; f < 4; ++f)
                b[f] = *reinterpret_cast<const short8*>(
                    &Wp[((size_t)k8 * 512 + colw + (f << 4) + l16) << 3]);
            #pragma unroll
            for (int m = 0; m < 8; ++m) {
                const short8 a = *reinterpret_cast<const short8*>(
                    &As[(m * 16 + l16) * 72 + (kt << 5) + (quad << 3)]);
                #pragma unroll
                for (int f = 0; f < 4; ++f)
                    acc[m][f] = __builtin_amdgcn_mfma_f32_16x16x32_bf16(a, b[f], acc[m][f], 0, 0, 0);
            }
        }
    }
    #pragma unroll
    for (int m = 0; m < 8; ++m)
        #pragma unroll
        for (int f = 0; f < 4; ++f) {
            const int col = colw + (f << 4) + l16;
            #pragma unroll
            for (int r = 0; r < 4; ++r) {
                const int row = row0 + m * 16 + quad * 4 + r;
                const unsigned short val = f2bf(acc[m][f][r]);
                if (packacc) {
                    const int rin = row & 63;
                    const int m_o = rin >> 4, q_o = (rin >> 2) & 3;
                    const int pr = (rin >> 1) & 1, h = rin & 1;
                    const int w_o = col >> 5, f_o = (col >> 4) & 1, l_o = col & 15;
                    const int tid_o = w_o * 64 + q_o * 16 + l_o;
                    const int jj = m_o * 8 + f_o * 4 + pr * 2 + h;
                    out0[((size_t)(row >> 6) * 1024 + tid_o) * 32 + jj] = val;
                } else {
                    out0[(size_t)row * 512 + col] = val;
                }
            }
        }
}

// ---- persistent integrator ----------------------------------------------------
struct OArgs {
    const float* x;              // fp32 input chunk [C,128]
    const unsigned short* W1zp;  // packed (K=128,N=512)
    const unsigned short* W2p;   // packed (K=512,N=512)
    const unsigned short* W3p;   // packed (K=512,N=128)
    const unsigned short* W2Tp;  // packed (K=512,N=512)
    const unsigned short* g3a;   // bf16 acc-packed [C/64][1024][32]
    const unsigned short* ua;    // bf16 acc-packed [C/64][1024][32]
    const float* b1;
    const float* w1t;            // W1 row 128 (t coefficients)
    const float* b2;
    const float* b3;
    float* z;                    // fp32 [C,128] out (for final_k)
    float* lp;                   // fp32 [C]
};

__global__ __launch_bounds__(1024, 4) void ode_k(OArgs p) {
    __shared__ __align__(16) unsigned short H1s[ROWS * PAN_STR]; // 68.6 KB h1 -> g2 panel
    __shared__ __align__(16) unsigned short Hss[ROWS * PAN_STR]; // 68.6 KB h2 panel
    __shared__ __align__(16) unsigned short Zss[ROWS * ZS_STR];  // 17.4 KB zs panel
    __shared__ float div_s[ROWS * 17];                           //  4.3 KB div partials
    const int tid  = threadIdx.x;
    const int wave = tid >> 6, lane = tid & 63;
    const int quad = lane >> 4, l16 = lane & 15;
    const int row0 = blockIdx.x * ROWS;
    const int colw = wave << 5;            // phases Z/A/D: 32 cols per wave (16 waves)
    const int colB = ((wave & 7) << 4) + l16;   // phase B column (0..127)
    const int rowB = (wave >> 3) << 5;          // phase B row half (0 or 32)

    // ---- per-chunk constants pinned in registers: acc-packed contiguous loads ----
    // dword index d = m*4 + f*2 + pr holds rows (pr*2 | pr*2+1 << 16) at this thread's
    // (m,f) acc position. Loaded as 4x dwordx4 (contiguous 64B/thread = no-remat pattern).
    uintx4 g3q[4], uq[4];
    {
        const uintx4* gsrc = reinterpret_cast<const uintx4*>(
            p.g3a + ((size_t)blockIdx.x * 1024 + tid) * 32);
        const uintx4* usrc = reinterpret_cast<const uintx4*>(
            p.ua + ((size_t)blockIdx.x * 1024 + tid) * 32);
        #pragma unroll
        for (int q = 0; q < 4; ++q) { g3q[q] = gsrc[q]; uq[q] = usrc[q]; }
    }
    float b1v[2], w1tv[2], b2v[2];
    #pragma unroll
    for (int f = 0; f < 2; ++f) {
        const int col = colw + (f << 4) + l16;
        b1v[f] = p.b1[col]; w1tv[f] = p.w1t[col]; b2v[f] = p.b2[col];
    }
    const float b3v = p.b3[colB];

    // ---- state in registers (phase-B mapping: row=rowB+m*16+quad*4+r, col=colB) ----
    float z_r[2][4];
    #pragma unroll
    for (int m = 0; m < 2; ++m)
        #pragma unroll
        for (int r = 0; r < 4; ++r) {
            const int row = rowB + m * 16 + quad * 4 + r;
            const float val = p.x[(size_t)(row0 + row) * 128 + colB];
            z_r[m][r] = val;
            Zss[row * ZS_STR + colB] = f2bf(val);
        }
    float accf_r[2][4];
    float accd_r = 0.0f, lp_r = 0.0f;

    const float dt = 1.0f / 32.0f;
    floatx4 acc[4][2];                     // shared by phases Z/A/D
    unsigned int facp[16];                 // fac=(1-h1^2)*u packed bf16, idx d=m*4+f*2+pr
    __syncthreads();                       // Zss init visible

    for (int e = 0; e < 128; ++e) {
        const int s = e & 3;
        const int step = e >> 2;
        const bool s0 = (s == 0), s3 = (s == 3);
        const float tph  = (s == 0) ? 0.0f : (s == 3 ? dt : 0.5f * dt);
        const float t    = (float)step * dt + tph;
        const float wrk  = (s == 1 || s == 2) ? (dt / 3.0f) : (dt / 6.0f);
        const float cnext = (s <= 1) ? 0.5f * dt : (s == 2 ? dt : 0.0f);

        // ===== phase Z: h1 = tanh(zs @ W1z + t*w1t + b1) -> H1s ; fac regs =====
        #pragma unroll
        for (int m = 0; m < 4; ++m)
            #pragma unroll
            for (int f = 0; f < 2; ++f) { floatx4 zz = {0.f,0.f,0.f,0.f}; acc[m][f] = zz; }
        #pragma unroll
        for (int kt = 0; kt < 4; ++kt) {
            const int k8 = (kt << 2) + quad;
            short8 b[2];
            #pragma unroll
            for (int f = 0; f < 2; ++f)
                b[f] = *reinterpret_cast<const short8*>(
                    &p.W1zp[((size_t)k8 * 512 + colw + (f << 4) + l16) << 3]);
            #pragma unroll
            for (int m = 0; m < 4; ++m) {
                const short8 a = *reinterpret_cast<const short8*>(
                    &Zss[(m * 16 + l16) * ZS_STR + (kt << 5) + (quad << 3)]);
                #pragma unroll
                for (int f = 0; f < 2; ++f)
                    acc[m][f] = __builtin_amdgcn_mfma_f32_16x16x32_bf16(a, b[f], acc[m][f], 0, 0, 0);
            }
        }
        #pragma unroll
        for (int m = 0; m < 4; ++m)
            #pragma unroll
            for (int f = 0; f < 2; ++f) {
                const int col = colw + (f << 4) + l16;
                const float bias = b1v[f] + t * w1tv[f];
                #pragma unroll
                for (int pr = 0; pr < 2; ++pr) {
                    const int d = m * 4 + f * 2 + pr;
                    const unsigned int upair = uq[d >> 2][d & 3];
                    unsigned int fp = 0;
                    #pragma unroll
                    for (int h = 0; h < 2; ++h) {
                        const int r = pr * 2 + h;
                        const int row = m * 16 + quad * 4 + r;
                        const unsigned short hb = f2bf(fast_tanh(acc[m][f][r] + bias));
                        H1s[row * PAN_STR + col] = hb;
                        const float thr = bf2f(hb);
                        const float uu  = bf2f((unsigned short)(upair >> (h << 4)));
                        const float fac = fmaf(-thr * thr, uu, uu);   // (1-h1^2)*u
                        fp |= (unsigned int)f2bf(fac) << (h << 4);
                    }
                    facp[d] = fp;
                }
            }
        __syncthreads();   // (2) H1s (h1) ready

        // ===== phase A mfma: h1 @ W2 =========================================
        #pragma unroll
        for (int m = 0; m < 4; ++m)
            #pragma unroll
            for (int f = 0; f < 2; ++f) { floatx4 zz = {0.f,0.f,0.f,0.f}; acc[m][f] = zz; }
        #pragma unroll 4
        for (int kt = 0; kt < 16; ++kt) {
            const int k8 = (kt << 2) + quad;
            short8 b[2];
            #pragma unroll
            for (int f = 0; f < 2; ++f)
                b[f] = *reinterpret_cast<const short8*>(
                    &p.W2p[((size_t)k8 * 512 + colw + (f << 4) + l16) << 3]);
            #pragma unroll
            for (int m = 0; m < 4; ++m) {
                const short8 a = *reinterpret_cast<const short8*>(
                    &H1s[(m * 16 + l16) * PAN_STR + (kt << 5) + (quad << 3)]);
                #pragma unroll
                for (int f = 0; f < 2; ++f)
                    acc[m][f] = __builtin_amdgcn_mfma_f32_16x16x32_bf16(a, b[f], acc[m][f], 0, 0, 0);
            }
        }
        __syncthreads();   // (3a) all h1 reads done -> H1s reusable

        // ===== phase A epi: h2 -> Hss ; g2 = g3*(1-h2^2) -> H1s ===============
        #pragma unroll
        for (int m = 0; m < 4; ++m)
            #pragma unroll
            for (int f = 0; f < 2; ++f) {
                const int col = colw + (f << 4) + l16;
                #pragma unroll
                for (int r = 0; r < 4; ++r) {
                    const int row = m * 16 + quad * 4 + r;
                    const unsigned short h2b = f2bf(fast_tanh(acc[m][f][r] + b2v[f]));
                    Hss[row * PAN_STR + col] = h2b;
                    const float h2r = bf2f(h2b);
                    const int d = m * 4 + f * 2 + (r >> 1);
                    const float g3f = bf2f((unsigned short)(g3q[d >> 2][d & 3] >> ((r & 1) << 4)));
                    const float gh  = g3f * h2r;
                    H1s[row * PAN_STR + col] = f2bf(fmaf(-gh, h2r, g3f));
                }
            }
        __syncthreads();   // (3b) h2 + g2 panels ready

        // ===== phase B: f = h2 @ W3 + b3 ; z/accf regs ; zs -> Zss =============
        {
            floatx4 accb[2];
            #pragma unroll
            for (int m = 0; m < 2; ++m) { floatx4 zz = {0.f,0.f,0.f,0.f}; accb[m] = zz; }
            #pragma unroll 4
            for (int kt = 0; kt < 16; ++kt) {
                const int k8 = (kt << 2) + quad;
                const short8 b = *reinterpret_cast<const short8*>(
                    &p.W3p[((size_t)k8 * 128 + colB) << 3]);
                #pragma unroll
                for (int m = 0; m < 2; ++m) {
                    const short8 a = *reinterpret_cast<const short8*>(
                        &Hss[(rowB + m * 16 + l16) * PAN_STR + (kt << 5) + (quad << 3)]);
                    accb[m] = __builtin_amdgcn_mfma_f32_16x16x32_bf16(a, b, accb[m], 0, 0, 0);
                }
            }
            #pragma unroll
            for (int m = 0; m < 2; ++m) {
                #pragma unroll
                for (int r = 0; r < 4; ++r) {
                    const int row = rowB + m * 16 + quad * 4 + r;
                    const float x = accb[m][r] + b3v;
                    const float a = wrk * x + (s0 ? 0.0f : accf_r[m][r]);
                    if (s3) {
                        z_r[m][r] += a;                       // z += dt/6 * sum(k)
                        Zss[row * ZS_STR + colB] = f2bf(z_r[m][r]);
                    } else {
                        accf_r[m][r] = a;
                        Zss[row * ZS_STR + colB] = f2bf(z_r[m][r] + cnext * x);
                    }
                }
            }
        }

        // ===== phase D: g1' = g2 @ W2^T ; div partials in-register =============
        #pragma unroll
        for (int m = 0; m < 4; ++m)
            #pragma unroll
            for (int f = 0; f < 2; ++f) { floatx4 zz = {0.f,0.f,0.f,0.f}; acc[m][f] = zz; }
        #pragma unroll 4
        for (int kt = 0; kt < 16; ++kt) {
            const int k8 = (kt << 2) + quad;
            short8 b[2];
            #pragma unroll
            for (int f = 0; f < 2; ++f)
                b[f] = *reinterpret_cast<const short8*>(
                    &p.W2Tp[((size_t)k8 * 512 + colw + (f << 4) + l16) << 3]);
            #pragma unroll
            for (int m = 0; m < 4; ++m) {
                const short8 a = *reinterpret_cast<const short8*>(
                    &H1s[(m * 16 + l16) * PAN_STR + (kt << 5) + (quad << 3)]);
                #pragma unroll
                for (int f = 0; f < 2; ++f)
                    acc[m][f] = __builtin_amdgcn_mfma_f32_16x16x32_bf16(a, b[f], acc[m][f], 0, 0, 0);
            }
        }
        #pragma unroll
        for (int m = 0; m < 4; ++m)
            #pragma unroll
            for (int r = 0; r < 4; ++r) {
                const int d0 = m * 4 + (r >> 1);
                const int d1 = m * 4 + 2 + (r >> 1);
                float pdv = acc[m][0][r] * bf2f((unsigned short)(facp[d0] >> ((r & 1) << 4)))
                          + acc[m][1][r] * bf2f((unsigned short)(facp[d1] >> ((r & 1) << 4)));
                pdv += __shfl_xor(pdv, 1);
                pdv += __shfl_xor(pdv, 2);
                pdv += __shfl_xor(pdv, 4);
                pdv += __shfl_xor(pdv, 8);
                if (l16 == 0) div_s[(m * 16 + quad * 4 + r) * 17 + wave] = pdv;
            }
        __syncthreads();   // (4) div_s + Zss ready; all panel reads done

        // ===== div reduce: accd/lp on (tid&15)==0 lanes, row tid>>4 ============
        {
            float part = div_s[(tid >> 4) * 17 + (tid & 15)];
            part += __shfl_xor(part, 1);
            part += __shfl_xor(part, 2);
            part += __shfl_xor(part, 4);
            part += __shfl_xor(part, 8);
            const float a = wrk * (-part) + (s0 ? 0.0f : accd_r);
            if (s3) lp_r += a;
            else    accd_r = a;
        }
    }

    // ---- write final state ----
    #pragma unroll
    for (int m = 0; m < 2; ++m)
        #pragma unroll
        for (int r = 0; r < 4; ++r)
            p.z[(size_t)(row0 + rowB + m * 16 + quad * 4 + r) * 128 + colB] = z_r[m][r];
    if ((tid & 15) == 0) p.lp[row0 + (tid >> 4)] = lp_r;
}

// out[b] = lp[b] - 0.5*||z||^2 - 0.5*128*log(2*pi)
__global__ void final_k(const float* __restrict__ z, const float* __restrict__ lp,
                        float* __restrict__ out) {
    const int tid = threadIdx.x;
    const int row = blockIdx.x * 16 + (tid >> 4);
    const int l16 = tid & 15;
    const float4* zr = (const float4*)&z[(size_t)row * 128 + (l16 << 3)];
    float4 a = zr[0], b = zr[1];
    float s = a.x*a.x + a.y*a.y + a.z*a.z + a.w*a.w
            + b.x*b.x + b.y*b.y + b.z*b.z + b.w*b.w;
    s += __shfl_xor(s, 1);
    s += __shfl_xor(s, 2);
    s += __shfl_xor(s, 4);
    s += __shfl_xor(s, 8);
    if (l16 == 0) out[row] = lp[row] - 0.5f * s - 117.6241322501981f;
}

extern "C" void kernel_launch(void* const* d_in, const int* in_sizes, int n_in,
                              void* d_out, int out_size, void* d_ws, size_t ws_size,
                              hipStream_t stream) {
    (void)n_in; (void)out_size;
    const float* x  = (const float*)d_in[0];
    const float* v  = (const float*)d_in[1];
    const float* W1 = (const float*)d_in[2];
    const float* b1 = (const float*)d_in[3];
    const float* W2 = (const float*)d_in[4];
    const float* b2 = (const float*)d_in[5];
    const float* W3 = (const float*)d_in[6];
    const float* b3 = (const float*)d_in[7];
    float* out = (float*)d_out;
    const int B = in_sizes[0] / DIMV;   // 65536

    auto al = [](size_t s) { return (s + 255) & ~(size_t)255; };
    auto need_for = [&](size_t C) {
        size_t s = 0;
        s += al(C * DIMV * 4);       // z
        s += al(C * 4);              // lp
        s += al(C * HIDV * 2) * 2;   // g3a, ua
        s += al(128 * 512 * 2) * 3 + al(512 * 512 * 2) * 2; // packed weights
        return s;
    };
    size_t C = 32768;
    while (C > 1024 && need_for(C) > ws_size) C >>= 1;
    if (need_for(C) > ws_size) return;  // cannot run safely in this workspace
    if (C > (size_t)B) C = B;

    char* w = (char*)d_ws;
    auto alloc = [&](size_t bytes) { char* p = w; w += al(bytes); return p; };
    float* z    = (float*)alloc(C * DIMV * 4);
    float* lp   = (float*)alloc(C * 4);
    unsigned short* g3a = (unsigned short*)alloc(C * HIDV * 2);
    unsigned short* ua  = (unsigned short*)alloc(C * HIDV * 2);
    unsigned short* W1zp  = (unsigned short*)alloc(128 * 512 * 2);
    unsigned short* W3p   = (unsigned short*)alloc(512 * 128 * 2);
    unsigned short* W3Tp  = (unsigned short*)alloc(128 * 512 * 2);
    unsigned short* W2p   = (unsigned short*)alloc(512 * 512 * 2);
    unsigned short* W2Tp  = (unsigned short*)alloc(512 * 512 * 2);

    auto pack = [&](const float* src, unsigned short* dst, int K, int N, int ld, int tr) {
        pack_kernel<<<dim3((K * N + 255) / 256), dim3(256), 0, stream>>>(src, dst, K, N, ld, tr);
    };
    pack(W1, W1zp,  128, 512, 512, 0);
    pack(W2, W2p,   512, 512, 512, 0);
    pack(W3, W3p,   512, 128, 128, 0);
    pack(W2, W2Tp,  512, 512, 512, 1);
    pack(W3, W3Tp,  128, 512, 128, 1);

    const int GM128 = (int)C / 128;
    const int GMF   = (int)C / ROWS;

    for (int c0 = 0; c0 < B; c0 += (int)C) {
        const float* xc = x + (size_t)c0 * DIMV;
        const float* vc = v + (size_t)c0 * DIMV;

        // g3 = v @ W3^T ; u = v @ W1z  (once per chunk, acc-packed for ode_k pinning)
        vg_k<<<dim3(GM128, 2), 256, 0, stream>>>(vc, W3Tp, g3a, 1);
        vg_k<<<dim3(GM128, 2), 256, 0, stream>>>(vc, W1zp, ua, 1);

        // full 32-step RK4 integration in one persistent dispatch
        OArgs q{};
        q.x = xc;
        q.W1zp = W1zp; q.W2p = W2p; q.W3p = W3p; q.W2Tp = W2Tp;
        q.g3a = g3a; q.ua = ua;
        q.b1 = b1; q.w1t = W1 + 128 * 512; q.b2 = b2; q.b3 = b3;
        q.z = z; q.lp = lp;
        ode_k<<<dim3(GMF), 1024, 0, stream>>>(q);

        final_k<<<dim3((int)C / 16), 256, 0, stream>>>(z, lp, out + c0);
    }
}

// Round 14
// 22599.686 us; speedup vs baseline: 1.2918x; 1.2918x over previous
//
#include <hip/hip_runtime.h>

// FFJORD density on MI355X (gfx950). B=65536 rows, DIM=128, HID=512, 32 RK4 steps x 4 evals.
// Round 16: barrier/overlap surgery on R9 (best: 19.86ms) with NO persistent register adds.
// Ledger: fusion w/ pinned constants remats (R10/R11/R15: FETCH 20-40GB); setprio null (R14);
// 2 blocks/CU worse (R7); pin-u worse (R12). This round relaxes the dependency graph:
//  - C' writes g2 into H1s (h1's last panel use is A's MFMA) and folds E's (1-h1^2)*u into
//    a TRANSIENT fac reg (16 VGPR, live C'->E only, recomputed per eval - not pinned).
//  - C' merges into B's phase (both read-only on Hss; C' writes H1s which B never touches)
//    -> C's VALU stream overlaps B's MFMA across drifting waves.
//  - D reads H1s(g2), writes Hss(g1') -> no in-place hazard -> no pre-epi barrier.
//  - E = sum(g1' * fac): no H1s re-read, no u load, half the ops.
//  - Barriers 7 -> 4/eval (re-derived: old (1) and (6) redundant in the new graph).
// Phase chain: Z(Zss->H1s h1) |2| A(H1s->Hss h2) |3| B(Hss->state,Zss) + C'(Hss,H1s,u ->
// H1s g2, fac regs) |4| D(H1s->Hss g1', epi direct) |5| E(Hss x fac -> accd/lp).
// 64-row blocks, 1024 thr, 16 waves, 1 block/CU (LDS 155KB), C=32768.
// Canaries: WRITE >1MB = spill; FETCH >15GB/dispatch = remat -> rollback to R9.

#define DIMV 128
#define HIDV 512
#define ROWS 64
#define PAN_STR 536   // panel stride (shorts): 1072B, 16B-aligned, 12-dword bank shift/row
#define ZS_STR  136   // 272B, 16B-aligned

typedef float  floatx4 __attribute__((ext_vector_type(4)));
typedef short  short8  __attribute__((ext_vector_type(8)));

static __device__ __forceinline__ unsigned short f2bf(float x) {
    union { float f; unsigned int u; } c; c.f = x;
    unsigned int u = c.u;
    u += 0x7FFFu + ((u >> 16) & 1u);   // round-to-nearest-even
    return (unsigned short)(u >> 16);
}
static __device__ __forceinline__ float bf2f(unsigned short h) {
    union { unsigned int u; float f; } c; c.u = ((unsigned int)h) << 16;
    return c.f;
}
static __device__ __forceinline__ float fast_tanh(float x) {
    x = fminf(8.0f, fmaxf(-8.0f, x));
    float e = exp2f(x * 2.8853900817779268f);            // exp(2x)
    return (e - 1.0f) * __builtin_amdgcn_rcpf(e + 1.0f); // (e-1)/(e+1)
}

// ---- weight packing: dst[(k>>3)*N*8 + n*8 + (k&7)] = bf16(W[k][n]) ------------
__global__ void pack_kernel(const float* __restrict__ src, unsigned short* __restrict__ dst,
                            int K, int N, int ld, int transpose) {
    int i = blockIdx.x * 256 + threadIdx.x;
    if (i >= K * N) return;
    int j  = i & 7;
    int n  = (i >> 3) % N;
    int k8 = (i >> 3) / N;
    int k  = k8 * 8 + j;
    float v = transpose ? src[n * ld + k] : src[k * ld + n];
    dst[i] = f2bf(v);
}

// ---- v-GEMM producer (g3 = v@W3^T, u = v@W1z): 128 rows x 256 cols per WG -----
__global__ __launch_bounds__(256, 2) void vg_k(const float* __restrict__ v,
                                               const unsigned short* __restrict__ Wp,
                                               unsigned short* __restrict__ out0) {
    __shared__ __align__(16) unsigned short As[128 * 72];
    const int tid  = threadIdx.x;
    const int wave = tid >> 6, lane = tid & 63;
    const int quad = lane >> 4, l16 = lane & 15;
    const int row0 = blockIdx.x * 128;
    const int colw = blockIdx.y * 256 + wave * 64;

    floatx4 acc[8][4];
    #pragma unroll
    for (int m = 0; m < 8; ++m)
        #pragma unroll
        for (int f = 0; f < 4; ++f) { floatx4 zz = {0.f,0.f,0.f,0.f}; acc[m][f] = zz; }

    for (int k0 = 0; k0 < 128; k0 += 64) {
        __syncthreads();
        {
            const int r  = tid >> 3;
            const int cc = (tid & 7) << 3;
            #pragma unroll
            for (int i = 0; i < 4; ++i) {
                const int rr = r + (i << 5);
                const size_t base = (size_t)(row0 + rr) * 128 + k0 + cc;
                float vals[8];
                *(float4*)&vals[0] = *(const float4*)&v[base];
                *(float4*)&vals[4] = *(const float4*)&v[base + 4];
                short8 sv;
                #pragma unroll
                for (int j = 0; j < 8; ++j) sv[j] = (short)f2bf(vals[j]);
                *reinterpret_cast<short8*>(&As[rr * 72 + cc]) = sv;
            }
        }
        __syncthreads();
        #pragma unroll
        for (int kt = 0; kt < 2; ++kt) {
            const int k8 = (k0 >> 3) + (kt << 2) + quad;
            short8 b[4];
            #pragma unroll
            for (int f = 0; f < 4; ++f)
                b[f] = *reinterpret_cast<const short8*>(
                    &Wp[((size_t)k8 * 512 + colw + (f << 4) + l16) << 3]);
            #pragma unroll
            for (int m = 0; m < 8; ++m) {
                const short8 a = *reinterpret_cast<const short8*>(
                    &As[(m * 16 + l16) * 72 + (kt << 5) + (quad << 3)]);
                #pragma unroll
                for (int f = 0; f < 4; ++f)
                    acc[m][f] = __builtin_amdgcn_mfma_f32_16x16x32_bf16(a, b[f], acc[m][f], 0, 0, 0);
            }
        }
    }
    #pragma unroll
    for (int m = 0; m < 8; ++m)
        #pragma unroll
        for (int f = 0; f < 4; ++f) {
            const int col = colw + (f << 4) + l16;
            #pragma unroll
            for (int r = 0; r < 4; ++r) {
                const int row = row0 + m * 16 + quad * 4 + r;
                out0[(size_t)row * 512 + col] = f2bf(acc[m][f][r]);
            }
        }
}

// ---- persistent integrator ----------------------------------------------------
struct OArgs {
    const float* x;              // fp32 input chunk [C,128]
    const unsigned short* W1zp;  // packed (K=128,N=512)
    const unsigned short* W2p;   // packed (K=512,N=512)
    const unsigned short* W3p;   // packed (K=512,N=128)
    const unsigned short* W2Tp;  // packed (K=512,N=512)
    const unsigned short* g3;    // bf16 [C,512]  (per-chunk constant, pinned streaming)
    const unsigned short* u;     // bf16 [C,512]  (per-chunk constant, streamed in C')
    const float* b1;
    const float* w1t;            // W1 row 128 (t coefficients)
    const float* b2;
    const float* b3;
    float* z;                    // fp32 [C,128] out (for final_k)
    float* lp;                   // fp32 [C]
};

__global__ __launch_bounds__(1024, 4) void ode_k(OArgs p) {
    __shared__ __align__(16) unsigned short H1s[ROWS * PAN_STR]; // 68.6 KB h1 -> g2 panel
    __shared__ __align__(16) unsigned short Hss[ROWS * PAN_STR]; // 68.6 KB h2 -> g1' panel
    __shared__ __align__(16) unsigned short Zss[ROWS * ZS_STR];  // 17.4 KB zs panel
    const int tid  = threadIdx.x;
    const int wave = tid >> 6, lane = tid & 63;
    const int quad = lane >> 4, l16 = lane & 15;
    const int row0 = blockIdx.x * ROWS;
    const int colw = wave << 5;            // phases Z/A/D: 32 cols per wave (16 waves)
    const int sr = tid >> 4;               // streaming row 0..63 (16 threads/row)
    const int sc = (tid & 15) << 3;        // streaming col-base (shorts), 128 cols/pass
    const size_t gbase = (size_t)(row0 + sr) * 512;
    const int colB = ((wave & 7) << 4) + l16;   // phase B column (0..127)
    const int rowB = (wave >> 3) << 5;          // phase B row half (0 or 32)

    // ---- per-chunk constants pinned in registers (R9-proven pattern) ----
    short8 g3v[4];
    #pragma unroll
    for (int j = 0; j < 4; ++j)
        g3v[j] = *reinterpret_cast<const short8*>(&p.g3[gbase + sc + (j << 7)]);
    float b1v[2], w1tv[2], b2v[2];
    #pragma unroll
    for (int f = 0; f < 2; ++f) {
        const int col = colw + (f << 4) + l16;
        b1v[f] = p.b1[col]; w1tv[f] = p.w1t[col]; b2v[f] = p.b2[col];
    }
    const float b3v = p.b3[colB];

    // ---- state in registers (phase-B mapping: row=rowB+m*16+quad*4+r, col=colB) ----
    float z_r[2][4];
    #pragma unroll
    for (int m = 0; m < 2; ++m)
        #pragma unroll
        for (int r = 0; r < 4; ++r) {
            const int row = rowB + m * 16 + quad * 4 + r;
            const float val = p.x[(size_t)(row0 + row) * 128 + colB];
            z_r[m][r] = val;
            Zss[row * ZS_STR + colB] = f2bf(val);
        }
    float accf_r[2][4];
    float accd_r = 0.0f, lp_r = 0.0f;      // valid on tid&15==0 lanes

    const float dt = 1.0f / 32.0f;
    floatx4 acc[4][2];                     // shared by phases Z/A/D
    short8 facv[4];                        // fac=(1-h1^2)*u bf16, transient C'->E
    __syncthreads();                       // Zss init visible

    for (int e = 0; e < 128; ++e) {
        const int s = e & 3;
        const int step = e >> 2;
        const bool s0 = (s == 0), s3 = (s == 3);
        const float tph  = (s == 0) ? 0.0f : (s == 3 ? dt : 0.5f * dt);
        const float t    = (float)step * dt + tph;
        const float wrk  = (s == 1 || s == 2) ? (dt / 3.0f) : (dt / 6.0f);
        const float cnext = (s <= 1) ? 0.5f * dt : (s == 2 ? dt : 0.0f);

        // ===== phase Z: h1 = tanh(zs @ W1z + t*w1t + b1) -> H1s ================
        // (H1s last read by D's MFMA, closed by barrier (5) of prev eval; Zss last
        //  written in B of prev eval, closed by (4). No extra barrier needed here.)
        #pragma unroll
        for (int m = 0; m < 4; ++m)
            #pragma unroll
            for (int f = 0; f < 2; ++f) { floatx4 zz = {0.f,0.f,0.f,0.f}; acc[m][f] = zz; }
        #pragma unroll
        for (int kt = 0; kt < 4; ++kt) {
            const int k8 = (kt << 2) + quad;
            short8 b[2];
            #pragma unroll
            for (int f = 0; f < 2; ++f)
                b[f] = *reinterpret_cast<const short8*>(
                    &p.W1zp[((size_t)k8 * 512 + colw + (f << 4) + l16) << 3]);
            #pragma unroll
            for (int m = 0; m < 4; ++m) {
                const short8 a = *reinterpret_cast<const short8*>(
                    &Zss[(m * 16 + l16) * ZS_STR + (kt << 5) + (quad << 3)]);
                #pragma unroll
                for (int f = 0; f < 2; ++f)
                    acc[m][f] = __builtin_amdgcn_mfma_f32_16x16x32_bf16(a, b[f], acc[m][f], 0, 0, 0);
            }
        }
        #pragma unroll
        for (int m = 0; m < 4; ++m)
            #pragma unroll
            for (int f = 0; f < 2; ++f) {
                const int col = colw + (f << 4) + l16;
                const float bias = b1v[f] + t * w1tv[f];
                #pragma unroll
                for (int r = 0; r < 4; ++r) {
                    const int row = m * 16 + quad * 4 + r;
                    H1s[row * PAN_STR + col] = f2bf(fast_tanh(acc[m][f][r] + bias));
                }
            }
        __syncthreads();   // (2) H1s (h1) ready

        // ===== phase A: h2 = tanh(h1 @ W2 + b2) -> Hss =========================
        #pragma unroll
        for (int m = 0; m < 4; ++m)
            #pragma unroll
            for (int f = 0; f < 2; ++f) { floatx4 zz = {0.f,0.f,0.f,0.f}; acc[m][f] = zz; }
        #pragma unroll 4
        for (int kt = 0; kt < 16; ++kt) {
            const int k8 = (kt << 2) + quad;
            short8 b[2];
            #pragma unroll
            for (int f = 0; f < 2; ++f)
                b[f] = *reinterpret_cast<const short8*>(
                    &p.W2p[((size_t)k8 * 512 + colw + (f << 4) + l16) << 3]);
            #pragma unroll
            for (int m = 0; m < 4; ++m) {
                const short8 a = *reinterpret_cast<const short8*>(
                    &H1s[(m * 16 + l16) * PAN_STR + (kt << 5) + (quad << 3)]);
                #pragma unroll
                for (int f = 0; f < 2; ++f)
                    acc[m][f] = __builtin_amdgcn_mfma_f32_16x16x32_bf16(a, b[f], acc[m][f], 0, 0, 0);
            }
        }
        #pragma unroll
        for (int m = 0; m < 4; ++m)
            #pragma unroll
            for (int f = 0; f < 2; ++f) {
                const int col = colw + (f << 4) + l16;
                #pragma unroll
                for (int r = 0; r < 4; ++r) {
                    const int row = m * 16 + quad * 4 + r;
                    Hss[row * PAN_STR + col] = f2bf(fast_tanh(acc[m][f][r] + b2v[f]));
                }
            }
        __syncthreads();   // (3) Hss (h2) ready; all A-phase H1s reads done

        // ===== phase B: f = h2 @ W3 + b3 ; state ; Zss ==========================
        {
            floatx4 accb[2];
            #pragma unroll
            for (int m = 0; m < 2; ++m) { floatx4 zz = {0.f,0.f,0.f,0.f}; accb[m] = zz; }
            #pragma unroll 4
            for (int kt = 0; kt < 16; ++kt) {
                const int k8 = (kt << 2) + quad;
                const short8 b = *reinterpret_cast<const short8*>(
                    &p.W3p[((size_t)k8 * 128 + colB) << 3]);
                #pragma unroll
                for (int m = 0; m < 2; ++m) {
                    const short8 a = *reinterpret_cast<const short8*>(
                        &Hss[(rowB + m * 16 + l16) * PAN_STR + (kt << 5) + (quad << 3)]);
                    accb[m] = __builtin_amdgcn_mfma_f32_16x16x32_bf16(a, b, accb[m], 0, 0, 0);
                }
            }
            #pragma unroll
            for (int m = 0; m < 2; ++m) {
                #pragma unroll
                for (int r = 0; r < 4; ++r) {
                    const int row = rowB + m * 16 + quad * 4 + r;
                    const float x = accb[m][r] + b3v;
                    const float a = wrk * x + (s0 ? 0.0f : accf_r[m][r]);
                    if (s3) {
                        z_r[m][r] += a;                       // z += dt/6 * sum(k)
                        Zss[row * ZS_STR + colB] = f2bf(z_r[m][r]);
                    } else {
                        accf_r[m][r] = a;
                        Zss[row * ZS_STR + colB] = f2bf(z_r[m][r] + cnext * x);
                    }
                }
            }
        }
        // ===== phase C' (same phase as B — both read-only on Hss): =============
        // g2 = g3 - (g3*h2)*h2 -> H1s (over dead h1; each addr RW by one thread);
        // fac = (1-h1^2)*u -> transient regs for E.
        #pragma unroll
        for (int j = 0; j < 4; ++j) {
            const int cc = sc + (j << 7);
            const short8 h2v = *reinterpret_cast<const short8*>(&Hss[sr * PAN_STR + cc]);
            const short8 h1v = *reinterpret_cast<const short8*>(&H1s[sr * PAN_STR + cc]);
            const short8 uvv = *reinterpret_cast<const short8*>(&p.u[gbase + cc]);
            short8 g2o, fco;
            #pragma unroll
            for (int el = 0; el < 8; ++el) {
                const float h2 = bf2f((unsigned short)h2v[el]);
                const float g  = bf2f((unsigned short)g3v[j][el]);
                const float gh = g * h2;
                g2o[el] = (short)f2bf(fmaf(-gh, h2, g));
                const float h1 = bf2f((unsigned short)h1v[el]);
                const float uu = bf2f((unsigned short)uvv[el]);
                fco[el] = (short)f2bf(fmaf(-h1 * h1, uu, uu));
            }
            *reinterpret_cast<short8*>(&H1s[sr * PAN_STR + cc]) = g2o;
            facv[j] = fco;
        }
        __syncthreads();   // (4) g2 panel ready; Zss writes complete; Hss reads done

        // ===== phase D: g1' = g2 @ W2^T ; epi writes Hss directly (no hazard) ===
        #pragma unroll
        for (int m = 0; m < 4; ++m)
            #pragma unroll
            for (int f = 0; f < 2; ++f) { floatx4 zz = {0.f,0.f,0.f,0.f}; acc[m][f] = zz; }
        #pragma unroll 4
        for (int kt = 0; kt < 16; ++kt) {
            const int k8 = (kt << 2) + quad;
            short8 b[2];
            #pragma unroll
            for (int f = 0; f < 2; ++f)
                b[f] = *reinterpret_cast<const short8*>(
                    &p.W2Tp[((size_t)k8 * 512 + colw + (f << 4) + l16) << 3]);
            #pragma unroll
            for (int m = 0; m < 4; ++m) {
                const short8 a = *reinterpret_cast<const short8*>(
                    &H1s[(m * 16 + l16) * PAN_STR + (kt << 5) + (quad << 3)]);
                #pragma unroll
                for (int f = 0; f < 2; ++f)
                    acc[m][f] = __builtin_amdgcn_mfma_f32_16x16x32_bf16(a, b[f], acc[m][f], 0, 0, 0);
            }
        }
        #pragma unroll
        for (int m = 0; m < 4; ++m)
            #pragma unroll
            for (int f = 0; f < 2; ++f) {
                const int col = colw + (f << 4) + l16;
                #pragma unroll
                for (int r = 0; r < 4; ++r) {
                    const int row = m * 16 + quad * 4 + r;
                    Hss[row * PAN_STR + col] = f2bf(acc[m][f][r]);   // g1' (h2 dead)
                }
            }
        __syncthreads();   // (5) g1' ready; all D-phase H1s reads done

        // ===== phase E: div = rowsum(g1' * fac) ; accd/lp regs =================
        {
            float sum = 0.0f;
            #pragma unroll
            for (int j = 0; j < 4; ++j) {
                const int cc = sc + (j << 7);
                const short8 xv = *reinterpret_cast<const short8*>(&Hss[sr * PAN_STR + cc]);
                #pragma unroll
                for (int el = 0; el < 8; ++el)
                    sum += bf2f((unsigned short)xv[el]) * bf2f((unsigned short)facv[j][el]);
            }
            sum += __shfl_xor(sum, 1);
            sum += __shfl_xor(sum, 2);
            sum += __shfl_xor(sum, 4);
            sum += __shfl_xor(sum, 8);
            const float a = wrk * (-sum) + (s0 ? 0.0f : accd_r);
            if (s3) lp_r += a;
            else    accd_r = a;
        }
        // next eval: Z writes H1s (last read closed by (5)); E's Hss reads close
        // before next A-epi via (2)+(3). No top-of-loop barrier needed.
    }

    // ---- write final state ----
    #pragma unroll
    for (int m = 0; m < 2; ++m)
        #pragma unroll
        for (int r = 0; r < 4; ++r)
            p.z[(size_t)(row0 + rowB + m * 16 + quad * 4 + r) * 128 + colB] = z_r[m][r];
    if ((tid & 15) == 0) p.lp[row0 + sr] = lp_r;
}

// out[b] = lp[b] - 0.5*||z||^2 - 0.5*128*log(2*pi)
__global__ void final_k(const float* __restrict__ z, const float* __restrict__ lp,
                        float* __restrict__ out) {
    const int tid = threadIdx.x;
    const int row = blockIdx.x * 16 + (tid >> 4);
    const int l16 = tid & 15;
    const float4* zr = (const float4*)&z[(size_t)row * 128 + (l16 << 3)];
    float4 a = zr[0], b = zr[1];
    float s = a.x*a.x + a.y*a.y + a.z*a.z + a.w*a.w
            + b.x*b.x + b.y*b.y + b.z*b.z + b.w*b.w;
    s += __shfl_xor(s, 1);
    s += __shfl_xor(s, 2);
    s += __shfl_xor(s, 4);
    s += __shfl_xor(s, 8);
    if (l16 == 0) out[row] = lp[row] - 0.5f * s - 117.6241322501981f;
}

extern "C" void kernel_launch(void* const* d_in, const int* in_sizes, int n_in,
                              void* d_out, int out_size, void* d_ws, size_t ws_size,
                              hipStream_t stream) {
    (void)n_in; (void)out_size;
    const float* x  = (const float*)d_in[0];
    const float* v  = (const float*)d_in[1];
    const float* W1 = (const float*)d_in[2];
    const float* b1 = (const float*)d_in[3];
    const float* W2 = (const float*)d_in[4];
    const float* b2 = (const float*)d_in[5];
    const float* W3 = (const float*)d_in[6];
    const float* b3 = (const float*)d_in[7];
    float* out = (float*)d_out;
    const int B = in_sizes[0] / DIMV;   // 65536

    auto al = [](size_t s) { return (s + 255) & ~(size_t)255; };
    auto need_for = [&](size_t C) {
        size_t s = 0;
        s += al(C * DIMV * 4);       // z
        s += al(C * 4);              // lp
        s += al(C * HIDV * 2) * 2;   // g3, u
        s += al(128 * 512 * 2) * 3 + al(512 * 512 * 2) * 2; // packed weights
        return s;
    };
    size_t C = 32768;
    while (C > 1024 && need_for(C) > ws_size) C >>= 1;
    if (need_for(C) > ws_size) return;  // cannot run safely in this workspace
    if (C > (size_t)B) C = B;

    char* w = (char*)d_ws;
    auto alloc = [&](size_t bytes) { char* p = w; w += al(bytes); return p; };
    float* z    = (float*)alloc(C * DIMV * 4);
    float* lp   = (float*)alloc(C * 4);
    unsigned short* g3 = (unsigned short*)alloc(C * HIDV * 2);
    unsigned short* u  = (unsigned short*)alloc(C * HIDV * 2);
    unsigned short* W1zp  = (unsigned short*)alloc(128 * 512 * 2);
    unsigned short* W3p   = (unsigned short*)alloc(512 * 128 * 2);
    unsigned short* W3Tp  = (unsigned short*)alloc(128 * 512 * 2);
    unsigned short* W2p   = (unsigned short*)alloc(512 * 512 * 2);
    unsigned short* W2Tp  = (unsigned short*)alloc(512 * 512 * 2);

    auto pack = [&](const float* src, unsigned short* dst, int K, int N, int ld, int tr) {
        pack_kernel<<<dim3((K * N + 255) / 256), dim3(256), 0, stream>>>(src, dst, K, N, ld, tr);
    };
    pack(W1, W1zp,  128, 512, 512, 0);
    pack(W2, W2p,   512, 512, 512, 0);
    pack(W3, W3p,   512, 128, 128, 0);
    pack(W2, W2Tp,  512, 512, 512, 1);
    pack(W3, W3Tp,  128, 512, 128, 1);

    const int GM128 = (int)C / 128;
    const int GMF   = (int)C / ROWS;

    for (int c0 = 0; c0 < B; c0 += (int)C) {
        const float* xc = x + (size_t)c0 * DIMV;
        const float* vc = v + (size_t)c0 * DIMV;

        // g3 = v @ W3^T ; u = v @ W1z  (once per chunk)
        vg_k<<<dim3(GM128, 2), 256, 0, stream>>>(vc, W3Tp, g3);
        vg_k<<<dim3(GM128, 2), 256, 0, stream>>>(vc, W1zp, u);

        // full 32-step RK4 integration in one persistent dispatch
        OArgs q{};
        q.x = xc;
        q.W1zp = W1zp; q.W2p = W2p; q.W3p = W3p; q.W2Tp = W2Tp;
        q.g3 = g3; q.u = u;
        q.b1 = b1; q.w1t = W1 + 128 * 512; q.b2 = b2; q.b3 = b3;
        q.z = z; q.lp = lp;
        ode_k<<<dim3(GMF), 1024, 0, stream>>>(q);

        final_k<<<dim3((int)C / 16), 256, 0, stream>>>(z, lp, out + c0);
    }
}

// Round 15
// 19632.175 us; speedup vs baseline: 1.4870x; 1.1512x over previous
//
#include <hip/hip_runtime.h>

// FFJORD density on MI355X (gfx950). B=65536 rows, DIM=128, HID=512, 32 RK4 steps x 4 evals.
// Round 17: exact R9 (best: 19.86ms) + two minimal, attributable deltas:
//  1. u-prefetch with REAL cover: issue E's 4 u short8 loads right after phase D's MFMA
//     loop (before barrier 6). They overlap D's epilogue + 2 barriers (~2-3us) -- 10x the
//     ~0.2us L2-miss/L3-hit latency that R9's phase-E-issued loads expose. The 16 transient
//     VGPRs overlap only D's EPILOGUE (acc draining), not any MFMA loop (R16's mistake).
//  2. C=65536 single chunk: deletes one vg_k pair + one dispatch warm-up (~0.6ms observed).
// Ledger: setprio null (R14 A/B); all register-adds spanning MFMA phases spill/remat
// (R10/11/12/15/16); 2 blocks/CU worse (R7). Canary: WRITE >1MB = spill -> revert.
// Structure (7 barriers/eval, R9): Z: h1=tanh(zs@W1z+t*w1t+b1)->H1s | A: h2=tanh(h1@W2+b2)
// ->Hss | B: f=h2@W3+b3, z/accf regs, zs->Zss | C: Hss<-g3-(g3*h2)*h2 | D: Hss<-g2@W2^T
// [u prefetch here] | E: div=rowsum(Hss*(1-h1^2)*u) -> accd/lp regs.
// 64-row blocks, 1024 thr, 16 waves, 1 block/CU (LDS 155KB).

#define DIMV 128
#define HIDV 512
#define ROWS 64
#define PAN_STR 536   // panel stride (shorts): 1072B, 16B-aligned, 12-dword bank shift/row
#define ZS_STR  136   // 272B, 16B-aligned

typedef float  floatx4 __attribute__((ext_vector_type(4)));
typedef short  short8  __attribute__((ext_vector_type(8)));

static __device__ __forceinline__ unsigned short f2bf(float x) {
    union { float f; unsigned int u; } c; c.f = x;
    unsigned int u = c.u;
    u += 0x7FFFu + ((u >> 16) & 1u);   // round-to-nearest-even
    return (unsigned short)(u >> 16);
}
static __device__ __forceinline__ float bf2f(unsigned short h) {
    union { unsigned int u; float f; } c; c.u = ((unsigned int)h) << 16;
    return c.f;
}
static __device__ __forceinline__ float fast_tanh(float x) {
    x = fminf(8.0f, fmaxf(-8.0f, x));
    float e = exp2f(x * 2.8853900817779268f);            // exp(2x)
    return (e - 1.0f) * __builtin_amdgcn_rcpf(e + 1.0f); // (e-1)/(e+1)
}

// ---- weight packing: dst[(k>>3)*N*8 + n*8 + (k&7)] = bf16(W[k][n]) ------------
__global__ void pack_kernel(const float* __restrict__ src, unsigned short* __restrict__ dst,
                            int K, int N, int ld, int transpose) {
    int i = blockIdx.x * 256 + threadIdx.x;
    if (i >= K * N) return;
    int j  = i & 7;
    int n  = (i >> 3) % N;
    int k8 = (i >> 3) / N;
    int k  = k8 * 8 + j;
    float v = transpose ? src[n * ld + k] : src[k * ld + n];
    dst[i] = f2bf(v);
}

// ---- v-GEMM producer (g3 = v@W3^T, u = v@W1z): 128 rows x 256 cols per WG -----
__global__ __launch_bounds__(256, 2) void vg_k(const float* __restrict__ v,
                                               const unsigned short* __restrict__ Wp,
                                               unsigned short* __restrict__ out0) {
    __shared__ __align__(16) unsigned short As[128 * 72];
    const int tid  = threadIdx.x;
    const int wave = tid >> 6, lane = tid & 63;
    const int quad = lane >> 4, l16 = lane & 15;
    const int row0 = blockIdx.x * 128;
    const int colw = blockIdx.y * 256 + wave * 64;

    floatx4 acc[8][4];
    #pragma unroll
    for (int m = 0; m < 8; ++m)
        #pragma unroll
        for (int f = 0; f < 4; ++f) { floatx4 zz = {0.f,0.f,0.f,0.f}; acc[m][f] = zz; }

    for (int k0 = 0; k0 < 128; k0 += 64) {
        __syncthreads();
        {
            const int r  = tid >> 3;
            const int cc = (tid & 7) << 3;
            #pragma unroll
            for (int i = 0; i < 4; ++i) {
                const int rr = r + (i << 5);
                const size_t base = (size_t)(row0 + rr) * 128 + k0 + cc;
                float vals[8];
                *(float4*)&vals[0] = *(const float4*)&v[base];
                *(float4*)&vals[4] = *(const float4*)&v[base + 4];
                short8 sv;
                #pragma unroll
                for (int j = 0; j < 8; ++j) sv[j] = (short)f2bf(vals[j]);
                *reinterpret_cast<short8*>(&As[rr * 72 + cc]) = sv;
            }
        }
        __syncthreads();
        #pragma unroll
        for (int kt = 0; kt < 2; ++kt) {
            const int k8 = (k0 >> 3) + (kt << 2) + quad;
            short8 b[4];
            #pragma unroll
            for (int f = 0; f < 4; ++f)
                b[f] = *reinterpret_cast<const short8*>(
                    &Wp[((size_t)k8 * 512 + colw + (f << 4) + l16) << 3]);
            #pragma unroll
            for (int m = 0; m < 8; ++m) {
                const short8 a = *reinterpret_cast<const short8*>(
                    &As[(m * 16 + l16) * 72 + (kt << 5) + (quad << 3)]);
                #pragma unroll
                for (int f = 0; f < 4; ++f)
                    acc[m][f] = __builtin_amdgcn_mfma_f32_16x16x32_bf16(a, b[f], acc[m][f], 0, 0, 0);
            }
        }
    }
    #pragma unroll
    for (int m = 0; m < 8; ++m)
        #pragma unroll
        for (int f = 0; f < 4; ++f) {
            const int col = colw + (f << 4) + l16;
            #pragma unroll
            for (int r = 0; r < 4; ++r) {
                const int row = row0 + m * 16 + quad * 4 + r;
                out0[(size_t)row * 512 + col] = f2bf(acc[m][f][r]);
            }
        }
}

// ---- persistent integrator ----------------------------------------------------
struct OArgs {
    const float* x;              // fp32 input chunk [C,128]
    const unsigned short* W1zp;  // packed (K=128,N=512)
    const unsigned short* W2p;   // packed (K=512,N=512)
    const unsigned short* W3p;   // packed (K=512,N=128)
    const unsigned short* W2Tp;  // packed (K=512,N=512)
    const unsigned short* g3;    // bf16 [C,512]  (per-chunk constant, pinned streaming)
    const unsigned short* u;     // bf16 [C,512]  (per-chunk constant, prefetched in D)
    const float* b1;
    const float* w1t;            // W1 row 128 (t coefficients)
    const float* b2;
    const float* b3;
    float* z;                    // fp32 [C,128] out (for final_k)
    float* lp;                   // fp32 [C]
};

__global__ __launch_bounds__(1024, 4) void ode_k(OArgs p) {
    __shared__ __align__(16) unsigned short H1s[ROWS * PAN_STR]; // 68.6 KB h1 panel
    __shared__ __align__(16) unsigned short Hss[ROWS * PAN_STR]; // 68.6 KB h2/g2/g1' panel
    __shared__ __align__(16) unsigned short Zss[ROWS * ZS_STR];  // 17.4 KB zs panel
    const int tid  = threadIdx.x;
    const int wave = tid >> 6, lane = tid & 63;
    const int quad = lane >> 4, l16 = lane & 15;
    const int row0 = blockIdx.x * ROWS;
    const int colw = wave << 5;            // phases Z/A/D: 32 cols per wave (16 waves)
    const int sr = tid >> 4;               // streaming row 0..63 (16 threads/row)
    const int sc = (tid & 15) << 3;        // streaming col-base (shorts), 128 cols/pass
    const size_t gbase = (size_t)(row0 + sr) * 512;
    const int colB = ((wave & 7) << 4) + l16;   // phase B column (0..127)
    const int rowB = (wave >> 3) << 5;          // phase B row half (0 or 32)

    // ---- per-chunk constants pinned in registers ----
    short8 g3v[4];
    #pragma unroll
    for (int j = 0; j < 4; ++j)
        g3v[j] = *reinterpret_cast<const short8*>(&p.g3[gbase + sc + (j << 7)]);
    float b1v[2], w1tv[2], b2v[2];
    #pragma unroll
    for (int f = 0; f < 2; ++f) {
        const int col = colw + (f << 4) + l16;
        b1v[f] = p.b1[col]; w1tv[f] = p.w1t[col]; b2v[f] = p.b2[col];
    }
    const float b3v = p.b3[colB];

    // ---- state in registers (phase-B mapping: row=rowB+m*16+quad*4+r, col=colB) ----
    float z_r[2][4];
    #pragma unroll
    for (int m = 0; m < 2; ++m)
        #pragma unroll
        for (int r = 0; r < 4; ++r) {
            const int row = rowB + m * 16 + quad * 4 + r;
            const float val = p.x[(size_t)(row0 + row) * 128 + colB];
            z_r[m][r] = val;
            Zss[row * ZS_STR + colB] = f2bf(val);
        }
    float accf_r[2][4];
    float accd_r = 0.0f, lp_r = 0.0f;      // valid on tid&15==0 lanes

    const float dt = 1.0f / 32.0f;
    floatx4 acc[4][2];                     // shared by phases Z/A/D

    for (int e = 0; e < 128; ++e) {
        const int s = e & 3;
        const int step = e >> 2;
        const bool s0 = (s == 0), s3 = (s == 3);
        const float tph  = (s == 0) ? 0.0f : (s == 3 ? dt : 0.5f * dt);
        const float t    = (float)step * dt + tph;
        const float wrk  = (s == 1 || s == 2) ? (dt / 3.0f) : (dt / 6.0f);
        const float cnext = (s <= 1) ? 0.5f * dt : (s == 2 ? dt : 0.0f);

        __syncthreads();   // (1) close prev eval: E's H1s/Hss reads done; Zss writes visible

        // ===== phase Z: h1 = tanh(zs @ W1z + t*w1t + b1) -> H1s ================
        #pragma unroll
        for (int m = 0; m < 4; ++m)
            #pragma unroll
            for (int f = 0; f < 2; ++f) { floatx4 zz = {0.f,0.f,0.f,0.f}; acc[m][f] = zz; }
        #pragma unroll
        for (int kt = 0; kt < 4; ++kt) {
            const int k8 = (kt << 2) + quad;
            short8 b[2];
            #pragma unroll
            for (int f = 0; f < 2; ++f)
                b[f] = *reinterpret_cast<const short8*>(
                    &p.W1zp[((size_t)k8 * 512 + colw + (f << 4) + l16) << 3]);
            #pragma unroll
            for (int m = 0; m < 4; ++m) {
                const short8 a = *reinterpret_cast<const short8*>(
                    &Zss[(m * 16 + l16) * ZS_STR + (kt << 5) + (quad << 3)]);
                #pragma unroll
                for (int f = 0; f < 2; ++f)
                    acc[m][f] = __builtin_amdgcn_mfma_f32_16x16x32_bf16(a, b[f], acc[m][f], 0, 0, 0);
            }
        }
        #pragma unroll
        for (int m = 0; m < 4; ++m)
            #pragma unroll
            for (int f = 0; f < 2; ++f) {
                const int col = colw + (f << 4) + l16;
                const float bias = b1v[f] + t * w1tv[f];
                #pragma unroll
                for (int r = 0; r < 4; ++r) {
                    const int row = m * 16 + quad * 4 + r;
                    H1s[row * PAN_STR + col] = f2bf(fast_tanh(acc[m][f][r] + bias));
                }
            }
        __syncthreads();   // (2) H1s ready

        // ===== phase A: h2 = tanh(h1 @ W2 + b2) -> Hss =========================
        #pragma unroll
        for (int m = 0; m < 4; ++m)
            #pragma unroll
            for (int f = 0; f < 2; ++f) { floatx4 zz = {0.f,0.f,0.f,0.f}; acc[m][f] = zz; }
        #pragma unroll 4
        for (int kt = 0; kt < 16; ++kt) {
            const int k8 = (kt << 2) + quad;
            short8 b[2];
            #pragma unroll
            for (int f = 0; f < 2; ++f)
                b[f] = *reinterpret_cast<const short8*>(
                    &p.W2p[((size_t)k8 * 512 + colw + (f << 4) + l16) << 3]);
            #pragma unroll
            for (int m = 0; m < 4; ++m) {
                const short8 a = *reinterpret_cast<const short8*>(
                    &H1s[(m * 16 + l16) * PAN_STR + (kt << 5) + (quad << 3)]);
                #pragma unroll
                for (int f = 0; f < 2; ++f)
                    acc[m][f] = __builtin_amdgcn_mfma_f32_16x16x32_bf16(a, b[f], acc[m][f], 0, 0, 0);
            }
        }
        #pragma unroll
        for (int m = 0; m < 4; ++m)
            #pragma unroll
            for (int f = 0; f < 2; ++f) {
                const int col = colw + (f << 4) + l16;
                #pragma unroll
                for (int r = 0; r < 4; ++r) {
                    const int row = m * 16 + quad * 4 + r;
                    Hss[row * PAN_STR + col] = f2bf(fast_tanh(acc[m][f][r] + b2v[f]));
                }
            }
        __syncthreads();   // (3) Hss (h2) ready

        // ===== phase B: f = h2 @ W3 + b3 ; z/accf regs ; zs -> Zss =============
        {
            floatx4 accb[2];
            #pragma unroll
            for (int m = 0; m < 2; ++m) { floatx4 zz = {0.f,0.f,0.f,0.f}; accb[m] = zz; }
            #pragma unroll 4
            for (int kt = 0; kt < 16; ++kt) {
                const int k8 = (kt << 2) + quad;
                const short8 b = *reinterpret_cast<const short8*>(
                    &p.W3p[((size_t)k8 * 128 + colB) << 3]);
                #pragma unroll
                for (int m = 0; m < 2; ++m) {
                    const short8 a = *reinterpret_cast<const short8*>(
                        &Hss[(rowB + m * 16 + l16) * PAN_STR + (kt << 5) + (quad << 3)]);
                    accb[m] = __builtin_amdgcn_mfma_f32_16x16x32_bf16(a, b, accb[m], 0, 0, 0);
                }
            }
            #pragma unroll
            for (int m = 0; m < 2; ++m) {
                #pragma unroll
                for (int r = 0; r < 4; ++r) {
                    const int row = rowB + m * 16 + quad * 4 + r;
                    const float x = accb[m][r] + b3v;
                    const float a = wrk * x + (s0 ? 0.0f : accf_r[m][r]);
                    if (s3) {
                        z_r[m][r] += a;                       // z += dt/6 * sum(k)
                        Zss[row * ZS_STR + colB] = f2bf(z_r[m][r]);
                    } else {
                        accf_r[m][r] = a;
                        Zss[row * ZS_STR + colB] = f2bf(z_r[m][r] + cnext * x);
                    }
                }
            }
        }
        __syncthreads();   // (4) all h2 reads done before in-place C

        // ===== phase C: Hss <- g2 = g3 - (g3*h2)*h2  (pinned g3 regs) ==========
        #pragma unroll
        for (int j = 0; j < 4; ++j) {
            const int cc = sc + (j << 7);
            const short8 hv = *reinterpret_cast<const short8*>(&Hss[sr * PAN_STR + cc]);
            short8 ov;
            #pragma unroll
            for (int el = 0; el < 8; ++el) {
                const float h = bf2f((unsigned short)hv[el]);
                const float g = bf2f((unsigned short)g3v[j][el]);
                const float gh = g * h;
                ov[el] = (short)f2bf(fmaf(-gh, h, g));
            }
            *reinterpret_cast<short8*>(&Hss[sr * PAN_STR + cc]) = ov;
        }
        __syncthreads();   // (5) g2 ready

        // ===== phase D: Hss <- g2 @ W2^T ; u prefetch after MFMA ===============
        #pragma unroll
        for (int m = 0; m < 4; ++m)
            #pragma unroll
            for (int f = 0; f < 2; ++f) { floatx4 zz = {0.f,0.f,0.f,0.f}; acc[m][f] = zz; }
        #pragma unroll 4
        for (int kt = 0; kt < 16; ++kt) {
            const int k8 = (kt << 2) + quad;
            short8 b[2];
            #pragma unroll
            for (int f = 0; f < 2; ++f)
                b[f] = *reinterpret_cast<const short8*>(
                    &p.W2Tp[((size_t)k8 * 512 + colw + (f << 4) + l16) << 3]);
            #pragma unroll
            for (int m = 0; m < 4; ++m) {
                const short8 a = *reinterpret_cast<const short8*>(
                    &Hss[(m * 16 + l16) * PAN_STR + (kt << 5) + (quad << 3)]);
                #pragma unroll
                for (int f = 0; f < 2; ++f)
                    acc[m][f] = __builtin_amdgcn_mfma_f32_16x16x32_bf16(a, b[f], acc[m][f], 0, 0, 0);
            }
        }
        // -- u prefetch: issued here, consumed in E. Covered by D-epi + 2 barriers.
        //    Live range overlaps only D's EPILOGUE (acc drain), no MFMA loop.
        short8 uvv[4];
        #pragma unroll
        for (int j = 0; j < 4; ++j)
            uvv[j] = *reinterpret_cast<const short8*>(&p.u[gbase + sc + (j << 7)]);
        __syncthreads();   // (6) all g2 reads done before overwrite
        #pragma unroll
        for (int m = 0; m < 4; ++m)
            #pragma unroll
            for (int f = 0; f < 2; ++f) {
                const int col = colw + (f << 4) + l16;
                #pragma unroll
                for (int r = 0; r < 4; ++r) {
                    const int row = m * 16 + quad * 4 + r;
                    Hss[row * PAN_STR + col] = f2bf(acc[m][f][r]);
                }
            }
        __syncthreads();   // (7) g1' ready

        // ===== phase E: div = rowsum(g1' * (1-h1^2) * u) ; prefetched u ========
        {
            float sum = 0.0f;
            #pragma unroll
            for (int j = 0; j < 4; ++j) {
                const int cc = sc + (j << 7);
                const short8 xv = *reinterpret_cast<const short8*>(&Hss[sr * PAN_STR + cc]);
                const short8 hv = *reinterpret_cast<const short8*>(&H1s[sr * PAN_STR + cc]);
                #pragma unroll
                for (int el = 0; el < 8; ++el) {
                    const float x = bf2f((unsigned short)xv[el]);
                    const float h = bf2f((unsigned short)hv[el]);
                    const float uu = bf2f((unsigned short)uvv[j][el]);
                    sum += x * (1.0f - h * h) * uu;
                }
            }
            sum += __shfl_xor(sum, 1);
            sum += __shfl_xor(sum, 2);
            sum += __shfl_xor(sum, 4);
            sum += __shfl_xor(sum, 8);
            const float a = wrk * (-sum) + (s0 ? 0.0f : accd_r);
            if (s3) lp_r += a;
            else    accd_r = a;
        }
        // next eval's barrier (1) orders E's H1s/Hss reads vs Z's overwrites
    }

    // ---- write final state ----
    #pragma unroll
    for (int m = 0; m < 2; ++m)
        #pragma unroll
        for (int r = 0; r < 4; ++r)
            p.z[(size_t)(row0 + rowB + m * 16 + quad * 4 + r) * 128 + colB] = z_r[m][r];
    if ((tid & 15) == 0) p.lp[row0 + sr] = lp_r;
}

// out[b] = lp[b] - 0.5*||z||^2 - 0.5*128*log(2*pi)
__global__ void final_k(const float* __restrict__ z, const float* __restrict__ lp,
                        float* __restrict__ out) {
    const int tid = threadIdx.x;
    const int row = blockIdx.x * 16 + (tid >> 4);
    const int l16 = tid & 15;
    const float4* zr = (const float4*)&z[(size_t)row * 128 + (l16 << 3)];
    float4 a = zr[0], b = zr[1];
    float s = a.x*a.x + a.y*a.y + a.z*a.z + a.w*a.w
            + b.x*b.x + b.y*b.y + b.z*b.z + b.w*b.w;
    s += __shfl_xor(s, 1);
    s += __shfl_xor(s, 2);
    s += __shfl_xor(s, 4);
    s += __shfl_xor(s, 8);
    if (l16 == 0) out[row] = lp[row] - 0.5f * s - 117.6241322501981f;
}

extern "C" void kernel_launch(void* const* d_in, const int* in_sizes, int n_in,
                              void* d_out, int out_size, void* d_ws, size_t ws_size,
                              hipStream_t stream) {
    (void)n_in; (void)out_size;
    const float* x  = (const float*)d_in[0];
    const float* v  = (const float*)d_in[1];
    const float* W1 = (const float*)d_in[2];
    const float* b1 = (const float*)d_in[3];
    const float* W2 = (const float*)d_in[4];
    const float* b2 = (const float*)d_in[5];
    const float* W3 = (const float*)d_in[6];
    const float* b3 = (const float*)d_in[7];
    float* out = (float*)d_out;
    const int B = in_sizes[0] / DIMV;   // 65536

    auto al = [](size_t s) { return (s + 255) & ~(size_t)255; };
    auto need_for = [&](size_t C) {
        size_t s = 0;
        s += al(C * DIMV * 4);       // z
        s += al(C * 4);              // lp
        s += al(C * HIDV * 2) * 2;   // g3, u
        s += al(128 * 512 * 2) * 3 + al(512 * 512 * 2) * 2; // packed weights
        return s;
    };
    size_t C = 65536;
    while (C > 1024 && need_for(C) > ws_size) C >>= 1;
    if (need_for(C) > ws_size) return;  // cannot run safely in this workspace
    if (C > (size_t)B) C = B;

    char* w = (char*)d_ws;
    auto alloc = [&](size_t bytes) { char* p = w; w += al(bytes); return p; };
    float* z    = (float*)alloc(C * DIMV * 4);
    float* lp   = (float*)alloc(C * 4);
    unsigned short* g3 = (unsigned short*)alloc(C * HIDV * 2);
    unsigned short* u  = (unsigned short*)alloc(C * HIDV * 2);
    unsigned short* W1zp  = (unsigned short*)alloc(128 * 512 * 2);
    unsigned short* W3p   = (unsigned short*)alloc(512 * 128 * 2);
    unsigned short* W3Tp  = (unsigned short*)alloc(128 * 512 * 2);
    unsigned short* W2p   = (unsigned short*)alloc(512 * 512 * 2);
    unsigned short* W2Tp  = (unsigned short*)alloc(512 * 512 * 2);

    auto pack = [&](const float* src, unsigned short* dst, int K, int N, int ld, int tr) {
        pack_kernel<<<dim3((K * N + 255) / 256), dim3(256), 0, stream>>>(src, dst, K, N, ld, tr);
    };
    pack(W1, W1zp,  128, 512, 512, 0);
    pack(W2, W2p,   512, 512, 512, 0);
    pack(W3, W3p,   512, 128, 128, 0);
    pack(W2, W2Tp,  512, 512, 512, 1);
    pack(W3, W3Tp,  128, 512, 128, 1);

    const int GM128 = (int)C / 128;
    const int GMF   = (int)C / ROWS;

    for (int c0 = 0; c0 < B; c0 += (int)C) {
        const float* xc = x + (size_t)c0 * DIMV;
        const float* vc = v + (size_t)c0 * DIMV;

        // g3 = v @ W3^T ; u = v @ W1z  (once per chunk)
        vg_k<<<dim3(GM128, 2), 256, 0, stream>>>(vc, W3Tp, g3);
        vg_k<<<dim3(GM128, 2), 256, 0, stream>>>(vc, W1zp, u);

        // full 32-step RK4 integration in one persistent dispatch
        OArgs q{};
        q.x = xc;
        q.W1zp = W1zp; q.W2p = W2p; q.W3p = W3p; q.W2Tp = W2Tp;
        q.g3 = g3; q.u = u;
        q.b1 = b1; q.w1t = W1 + 128 * 512; q.b2 = b2; q.b3 = b3;
        q.z = z; q.lp = lp;
        ode_k<<<dim3(GMF), 1024, 0, stream>>>(q);

        final_k<<<dim3((int)C / 16), 256, 0, stream>>>(z, lp, out + c0);
    }
}